// Round 2
// baseline (782.484 us; speedup 1.0000x reference)
//
#include <hip/hip_runtime.h>
#include <hip/hip_fp16.h>
#include <hip/hip_cooperative_groups.h>
#include <math.h>

namespace cg = cooperative_groups;

#define N_NODES 30000
#define N_EDGES 480000
#define HEADS 4
#define DHEAD 64
#define FDIM 256   // HEADS * DHEAD
#define POSD 32
#define CAPB 96            // bucket capacity (max observed degree ~45)
#define HIST_NB 1875       // 1875 blocks x 256 = 480000 edges
#define G0_NB 940          // gemm blocks: 4 heads x 235 row-blocks
#define AGG_NB 7500        // (N_NODES+3)/4
#define PREP_NB 319        // 64 W0T + 3 PW0 + 118 degzero + 128 W1/W2T + 6 PW12

typedef _Float16 half8 __attribute__((ext_vector_type(8)));
typedef float floatx4 __attribute__((ext_vector_type(4)));

__device__ __forceinline__ float lrelu(float x){ return x > 0.f ? x : 0.2f * x; }

// ---------------- GEMM body ------------------------------------------------
// One head per tile-x (64 cols), 128 rows per tile-y; 4 waves x 32 rows.
template<typename T>
__device__ __forceinline__ void gemm_body(
    int bx, int by, const T* __restrict__ A, const _Float16* __restrict__ Wt,
    const float* __restrict__ PW, const int* __restrict__ pos,
    const float* __restrict__ al, const float* __restrict__ arw,
    _Float16* __restrict__ Ch, float* __restrict__ a1, float* __restrict__ a2,
    int K){
  int t = threadIdx.x;
  int w = t >> 6;
  int lane = t & 63;
  int lm = lane & 15;        // m (A) / n (B) / col (C)
  int kq = lane >> 4;        // quad
  int h = bx;                // head of this tile
  int rowBase = by * 128 + w * 32;
  int colBase = h * DHEAD;

  floatx4 acc[2][4] = {};

  const T* Ar[2];
#pragma unroll
  for (int r = 0; r < 2; r++)
    Ar[r] = A + (size_t)min(rowBase + r * 16 + lm, N_NODES - 1) * K;
  const _Float16* Bp[4];
#pragma unroll
  for (int j = 0; j < 4; j++)
    Bp[j] = Wt + (size_t)(colBase + j * 16 + lm) * K;

  for (int kb = 0; kb < K; kb += 32){
    int ko = kb + kq * 8;
    half8 bf[4];
#pragma unroll
    for (int j = 0; j < 4; j++) bf[j] = *(const half8*)(Bp[j] + ko);
#pragma unroll
    for (int r = 0; r < 2; r++){
      half8 af;
      if constexpr (sizeof(T) == 2){
        af = *(const half8*)(Ar[r] + ko);
      } else {
        float4 u0 = *(const float4*)(Ar[r] + ko);
        float4 u1 = *(const float4*)(Ar[r] + ko + 4);
        af[0] = (_Float16)u0.x; af[1] = (_Float16)u0.y;
        af[2] = (_Float16)u0.z; af[3] = (_Float16)u0.w;
        af[4] = (_Float16)u1.x; af[5] = (_Float16)u1.y;
        af[6] = (_Float16)u1.z; af[7] = (_Float16)u1.w;
      }
#pragma unroll
      for (int j = 0; j < 4; j++)
        acc[r][j] = __builtin_amdgcn_mfma_f32_16x16x32_f16(af, bf[j], acc[r][j], 0, 0, 0);
    }
  }

  float alw[4], arr[4];
#pragma unroll
  for (int j = 0; j < 4; j++){
    int col = j * 16 + lm;
    alw[j] = al [h * DHEAD + col];
    arr[j] = arw[h * DHEAD + col];
  }

#pragma unroll
  for (int r = 0; r < 2; r++){
#pragma unroll
    for (int p = 0; p < 4; p++){
      int row = rowBase + r * 16 + kq * 4 + p;
      if (row < N_NODES){
        int pz = pos[row];
        const float* pwb = PW + pz * FDIM + colBase;
        float s1 = 0.f, s2 = 0.f;
#pragma unroll
        for (int j = 0; j < 4; j++){
          float v = acc[r][j][p] + pwb[j * 16 + lm];
          Ch[(size_t)row * FDIM + colBase + j * 16 + lm] = (_Float16)v;
          s1 = fmaf(v, alw[j], s1);
          s2 = fmaf(v, arr[j], s2);
        }
#pragma unroll
        for (int o2 = 1; o2 <= 8; o2 <<= 1){
          s1 += __shfl_xor(s1, o2, 64);
          s2 += __shfl_xor(s2, o2, 64);
        }
        if (lm == 0){
          a1[row * HEADS + h] = s1;
          a2[row * HEADS + h] = s2;
        }
      }
    }
  }
}

// ---------------- prep block (virtual-block dispatch) ----------------------
// vb [0,64): W0 transpose; [64,67): PW0; [67,185): deg:=0;
// vb [185,313): W1/W2 transpose; [313,319): PW for layers 1/2
__device__ __forceinline__ void prep_block(
    int vb, const float* __restrict__ W0, const float* __restrict__ W1,
    const float* __restrict__ W2, const float* __restrict__ pe0,
    const float* __restrict__ pe1, const float* __restrict__ pe2,
    _Float16* __restrict__ T0, _Float16* __restrict__ T1,
    _Float16* __restrict__ T2, float* __restrict__ PW, int* __restrict__ deg){
  int n = threadIdx.x;
  if (vb < 64){
    for (int k = vb; k < 128; k += 64)
      T0[(size_t)n * 128 + k] = (_Float16)W0[(size_t)k * FDIM + n];
  } else if (vb < 67){
    int v = vb - 64;
    float s = 0.f;
#pragma unroll
    for (int k = 0; k < POSD; k++)
      s = fmaf(pe0[v * POSD + k], W0[(size_t)(128 + k) * FDIM + n], s);
    PW[v * FDIM + n] = s;
  } else if (vb < 185){
    int i = (vb - 67) * 256 + n;
    if (i < N_NODES) deg[i] = 0;
  } else if (vb < 313){
    int q = vb - 185;
    int l = q >> 6, kk0 = q & 63;
    const float* W = l == 0 ? W1 : W2;
    _Float16* T    = l == 0 ? T1 : T2;
    for (int k = kk0; k < 256; k += 64)
      T[(size_t)n * 256 + k] = (_Float16)W[(size_t)k * FDIM + n];
  } else {
    int q = vb - 313;
    int layer = q / 3 + 1, v = q % 3;
    const float* W  = layer == 1 ? W1 : W2;
    const float* pe = layer == 1 ? pe1 : pe2;
    float s = 0.f;
#pragma unroll
    for (int k = 0; k < POSD; k++)
      s = fmaf(pe[v * POSD + k], W[(size_t)(256 + k) * FDIM + n], s);
    PW[(layer * 3 + v) * FDIM + n] = s;
  }
}

// ---------------- aggregation body: one wave per node ----------------------
__device__ __forceinline__ void agg_block(
    int vb, const _Float16* __restrict__ ft, const float* __restrict__ a1,
    const float* __restrict__ a2, const int* __restrict__ degv,
    const int* __restrict__ esrc, _Float16* __restrict__ outh,
    float* __restrict__ outf, int mode){
  int wv = threadIdx.x >> 6;
  int lane = threadIdx.x & 63;
  int n = vb * 4 + wv;
  if (n >= N_NODES) return;   // wave-uniform; never called around grid.sync
  int jb = n * CAPB;
  int deg = min(degv[n], CAPB);
  int eidx = lane & 15, h = lane >> 4;
  int hsel = h << 4;
  float a2n = a2[n * HEADS + h];
  float4 acc = make_float4(0.f, 0.f, 0.f, 0.f);
  const _Float16* ftl = ft + lane * 4;
  struct h4 { __half2 a, b; };

  if (deg <= 64){
    int sreg[4]; float wreg[4];
    float m = -INFINITY;
#pragma unroll
    for (int r = 0; r < 4; r++){
      int idx = eidx + r * 16;
      int s = (idx < deg) ? esrc[jb + idx] : 0;
      sreg[r] = s;
      float e = (idx < deg) ? lrelu(a1[s * HEADS + h] + a2n) : -INFINITY;
      wreg[r] = e;
      m = fmaxf(m, e);
    }
    m = fmaxf(m, __shfl_xor(m, 1, 64));
    m = fmaxf(m, __shfl_xor(m, 2, 64));
    m = fmaxf(m, __shfl_xor(m, 4, 64));
    m = fmaxf(m, __shfl_xor(m, 8, 64));
    float ss = 0.f;
#pragma unroll
    for (int r = 0; r < 4; r++){
      int idx = eidx + r * 16;
      float tv = (idx < deg) ? __expf(wreg[r] - m) : 0.f;
      wreg[r] = tv;
      ss += tv;
    }
    ss += __shfl_xor(ss, 1, 64);
    ss += __shfl_xor(ss, 2, 64);
    ss += __shfl_xor(ss, 4, 64);
    ss += __shfl_xor(ss, 8, 64);
    float inv = (ss > 0.f) ? 1.f / ss : 0.f;
#pragma unroll
    for (int r = 0; r < 4; r++) wreg[r] *= inv;

#pragma unroll
    for (int r = 0; r < 4; r++){
      if (r * 16 >= deg) break;
      int lim = deg - r * 16; if (lim > 16) lim = 16;
      float wr = wreg[r]; int sr = sreg[r];
      int jj = 0;
      for (; jj + 8 <= lim; jj += 8){
        float w8[8]; int s8[8]; h4 f8[8];
#pragma unroll
        for (int u = 0; u < 8; u++){
          w8[u] = __shfl(wr, (jj + u) | hsel, 64);
          s8[u] = __shfl(sr, jj + u, 64);
        }
#pragma unroll
        for (int u = 0; u < 8; u++)
          f8[u] = *(const h4*)(ftl + (size_t)s8[u] * FDIM);
#pragma unroll
        for (int u = 0; u < 8; u++){
          float2 fa = __half22float2(f8[u].a), fb = __half22float2(f8[u].b);
          acc.x = fmaf(w8[u], fa.x, acc.x);
          acc.y = fmaf(w8[u], fa.y, acc.y);
          acc.z = fmaf(w8[u], fb.x, acc.z);
          acc.w = fmaf(w8[u], fb.y, acc.w);
        }
      }
      for (; jj < lim; jj += 4){
        float w4[4]; int s4[4]; h4 f4[4];
#pragma unroll
        for (int u = 0; u < 4; u++){
          w4[u] = __shfl(wr, (jj + u) | hsel, 64);
          s4[u] = __shfl(sr, jj + u, 64);
        }
#pragma unroll
        for (int u = 0; u < 4; u++)
          f4[u] = *(const h4*)(ftl + (size_t)s4[u] * FDIM);
#pragma unroll
        for (int u = 0; u < 4; u++){
          float2 fa = __half22float2(f4[u].a), fb = __half22float2(f4[u].b);
          acc.x = fmaf(w4[u], fa.x, acc.x);
          acc.y = fmaf(w4[u], fa.y, acc.y);
          acc.z = fmaf(w4[u], fb.x, acc.z);
          acc.w = fmaf(w4[u], fb.y, acc.w);
        }
      }
    }
  } else {
    float m = -INFINITY;
    for (int idx = eidx; idx < deg; idx += 16){
      int s = esrc[jb + idx];
      m = fmaxf(m, lrelu(a1[s * HEADS + h] + a2n));
    }
    m = fmaxf(m, __shfl_xor(m, 1, 64));
    m = fmaxf(m, __shfl_xor(m, 2, 64));
    m = fmaxf(m, __shfl_xor(m, 4, 64));
    m = fmaxf(m, __shfl_xor(m, 8, 64));
    float ss = 0.f;
    for (int idx = eidx; idx < deg; idx += 16){
      int s = esrc[jb + idx];
      ss += __expf(lrelu(a1[s * HEADS + h] + a2n) - m);
    }
    ss += __shfl_xor(ss, 1, 64);
    ss += __shfl_xor(ss, 2, 64);
    ss += __shfl_xor(ss, 4, 64);
    ss += __shfl_xor(ss, 8, 64);
    float inv = (ss > 0.f) ? 1.f / ss : 0.f;
    for (int j = 0; j < deg; j++){
      int sj = esrc[jb + j];
      float e = lrelu(a1[sj * HEADS + h] + a2n);
      float wj = __expf(e - m) * inv;
      h4 f = *(const h4*)(ftl + (size_t)sj * FDIM);
      float2 fa = __half22float2(f.a), fb = __half22float2(f.b);
      acc.x = fmaf(wj, fa.x, acc.x);
      acc.y = fmaf(wj, fa.y, acc.y);
      acc.z = fmaf(wj, fb.x, acc.z);
      acc.w = fmaf(wj, fb.y, acc.w);
    }
  }

  if (mode == 0){
    acc.x = acc.x > 0.f ? acc.x : (__expf(acc.x) - 1.f);
    acc.y = acc.y > 0.f ? acc.y : (__expf(acc.y) - 1.f);
    acc.z = acc.z > 0.f ? acc.z : (__expf(acc.z) - 1.f);
    acc.w = acc.w > 0.f ? acc.w : (__expf(acc.w) - 1.f);
    struct h4s { _Float16 h[4]; } u;
    u.h[0] = (_Float16)acc.x; u.h[1] = (_Float16)acc.y;
    u.h[2] = (_Float16)acc.z; u.h[3] = (_Float16)acc.w;
    *(h4s*)&outh[(size_t)n * FDIM + lane * 4] = u;
  } else {
#pragma unroll
    for (int o2 = 16; o2 <= 32; o2 <<= 1){
      acc.x += __shfl_xor(acc.x, o2, 64);
      acc.y += __shfl_xor(acc.y, o2, 64);
      acc.z += __shfl_xor(acc.z, o2, 64);
      acc.w += __shfl_xor(acc.w, o2, 64);
    }
    if (lane < 16){
      float4 o;
      o.x = acc.x * 0.25f; o.y = acc.y * 0.25f;
      o.z = acc.z * 0.25f; o.w = acc.w * 0.25f;
      *(float4*)&outf[(size_t)n * DHEAD + lane * 4] = o;
    }
  }
}

// ---------------- param pack ----------------------------------------------
struct Params {
  const float* features;
  const float *W0, *al0, *ar0, *pe0;
  const float *W1, *al1, *ar1, *pe1;
  const float *W2, *al2, *ar2, *pe2;
  const int *src, *dst, *pos;
  float* out;
  _Float16 *fth, *hbuf, *Wt0, *Wt1, *Wt2;
  float *a1, *a2, *PW;
  int *deg, *esrc;
};

// ---------------- cooperative mega-kernel: whole pipeline ------------------
__global__ __launch_bounds__(256, 4) void mega_k(Params p){
  cg::grid_group grid = cg::this_grid();
  const int G = gridDim.x;

  // Stage A: transposes + PW tables + deg:=0
  for (int vb = blockIdx.x; vb < PREP_NB; vb += G)
    prep_block(vb, p.W0, p.W1, p.W2, p.pe0, p.pe1, p.pe2,
               p.Wt0, p.Wt1, p.Wt2, p.PW, p.deg);
  grid.sync();

  // Stage B: edge bucket scatter (first: long pole) + layer-0 gemm
  for (int vb = blockIdx.x; vb < HIST_NB + G0_NB; vb += G){
    if (vb < HIST_NB){
      int e = vb * 256 + threadIdx.x;
      if (e < N_EDGES){
        int d = p.dst[e];
        int slot = atomicAdd(&p.deg[d], 1);
        if (slot < CAPB) p.esrc[d * CAPB + slot] = p.src[e];
      }
    } else {
      int q = vb - HIST_NB;
      gemm_body<float>(q & 3, q >> 2, p.features, p.Wt0, p.PW, p.pos,
                       p.al0, p.ar0, p.fth, p.a1, p.a2, 128);
    }
  }
  grid.sync();

  // Stage C: agg layer 0
  for (int vb = blockIdx.x; vb < AGG_NB; vb += G)
    agg_block(vb, p.fth, p.a1, p.a2, p.deg, p.esrc, p.hbuf, nullptr, 0);
  grid.sync();

  // Stage D: gemm layer 1
  for (int vb = blockIdx.x; vb < G0_NB; vb += G)
    gemm_body<_Float16>(vb & 3, vb >> 2, p.hbuf, p.Wt1, p.PW + 3 * FDIM,
                        p.pos, p.al1, p.ar1, p.fth, p.a1, p.a2, 256);
  grid.sync();

  // Stage E: agg layer 1
  for (int vb = blockIdx.x; vb < AGG_NB; vb += G)
    agg_block(vb, p.fth, p.a1, p.a2, p.deg, p.esrc, p.hbuf, nullptr, 0);
  grid.sync();

  // Stage F: gemm layer 2
  for (int vb = blockIdx.x; vb < G0_NB; vb += G)
    gemm_body<_Float16>(vb & 3, vb >> 2, p.hbuf, p.Wt2, p.PW + 6 * FDIM,
                        p.pos, p.al2, p.ar2, p.fth, p.a1, p.a2, 256);
  grid.sync();

  // Stage G: agg layer 2, head-mean -> out
  for (int vb = blockIdx.x; vb < AGG_NB; vb += G)
    agg_block(vb, p.fth, p.a1, p.a2, p.deg, p.esrc, nullptr, p.out, 1);
}

// ---------------- fallback kernels (non-cooperative path) ------------------
__global__ __launch_bounds__(256) void prep0_k(
    const float* __restrict__ W0, const float* __restrict__ pe0,
    _Float16* __restrict__ T0, float* __restrict__ PW, int* __restrict__ deg){
  int blk = blockIdx.x, n = threadIdx.x;
  if (blk < 64){
    for (int k = blk; k < 128; k += 64)
      T0[(size_t)n * 128 + k] = (_Float16)W0[(size_t)k * FDIM + n];
  } else if (blk < 67){
    int v = blk - 64;
    float s = 0.f;
#pragma unroll
    for (int k = 0; k < POSD; k++)
      s = fmaf(pe0[v * POSD + k], W0[(size_t)(128 + k) * FDIM + n], s);
    PW[v * FDIM + n] = s;
  } else {
    int i = (blk - 67) * 256 + n;
    if (i < N_NODES) deg[i] = 0;
  }
}

__global__ __launch_bounds__(256, 2) void fused0_k(Params p){
  int blk = blockIdx.x;
  if (blk < G0_NB){
    gemm_body<float>(blk & 3, blk >> 2, p.features, p.Wt0, p.PW, p.pos,
                     p.al0, p.ar0, p.fth, p.a1, p.a2, 128);
  } else if (blk < G0_NB + HIST_NB){
    int e = (blk - G0_NB) * 256 + threadIdx.x;
    if (e < N_EDGES){
      int d = p.dst[e];
      int slot = atomicAdd(&p.deg[d], 1);
      if (slot < CAPB) p.esrc[d * CAPB + slot] = p.src[e];
    }
  } else if (blk < G0_NB + HIST_NB + 128 + 6){
    prep_block(blk - G0_NB - HIST_NB + 185, p.W0, p.W1, p.W2, p.pe0, p.pe1,
               p.pe2, p.Wt0, p.Wt1, p.Wt2, p.PW, p.deg);
  }
}

template<typename T>
__global__ __launch_bounds__(256, 2) void gemm_k(
    const T* __restrict__ A, const _Float16* __restrict__ Wt,
    const float* __restrict__ PW, const int* __restrict__ pos,
    const float* __restrict__ al, const float* __restrict__ arw,
    _Float16* __restrict__ Ch, float* __restrict__ a1, float* __restrict__ a2,
    int K){
  gemm_body<T>(blockIdx.x, blockIdx.y, A, Wt, PW, pos, al, arw, Ch, a1, a2, K);
}

__global__ __launch_bounds__(256) void agg4_k(
    const _Float16* __restrict__ ft, const float* __restrict__ a1,
    const float* __restrict__ a2, const int* __restrict__ degv,
    const int* __restrict__ esrc, _Float16* __restrict__ outh,
    float* __restrict__ outf, int mode){
  agg_block(blockIdx.x, ft, a1, a2, degv, esrc, outh, outf, mode);
}

// ---------------- launch ----------------
extern "C" void kernel_launch(void* const* d_in, const int* in_sizes, int n_in,
                              void* d_out, int out_size, void* d_ws, size_t ws_size,
                              hipStream_t stream){
  Params p;
  p.features = (const float*)d_in[0];
  p.W0  = (const float*)d_in[1];  p.al0 = (const float*)d_in[2];
  p.ar0 = (const float*)d_in[3];  p.pe0 = (const float*)d_in[4];
  p.W1  = (const float*)d_in[5];  p.al1 = (const float*)d_in[6];
  p.ar1 = (const float*)d_in[7];  p.pe1 = (const float*)d_in[8];
  p.W2  = (const float*)d_in[9];  p.al2 = (const float*)d_in[10];
  p.ar2 = (const float*)d_in[11]; p.pe2 = (const float*)d_in[12];
  p.src = (const int*)d_in[13];   p.dst = (const int*)d_in[14];
  p.pos = (const int*)d_in[15];
  p.out = (float*)d_out;

  char* wp = (char*)d_ws;
  auto alloc = [&](size_t bytes){
    void* q = (void*)wp;
    wp += (bytes + 255) & ~(size_t)255;
    return q;
  };
  p.fth  = (_Float16*)alloc(sizeof(_Float16) * (size_t)N_NODES * FDIM);
  p.hbuf = (_Float16*)alloc(sizeof(_Float16) * (size_t)N_NODES * FDIM);
  p.Wt0  = (_Float16*)alloc(sizeof(_Float16) * 256 * 128);
  p.Wt1  = (_Float16*)alloc(sizeof(_Float16) * 256 * 256);
  p.Wt2  = (_Float16*)alloc(sizeof(_Float16) * 256 * 256);
  p.a1   = (float*)alloc(sizeof(float) * N_NODES * HEADS);
  p.a2   = (float*)alloc(sizeof(float) * N_NODES * HEADS);
  p.PW   = (float*)alloc(sizeof(float) * 9 * FDIM);
  p.deg  = (int*)alloc(sizeof(int) * N_NODES);
  p.esrc = (int*)alloc(sizeof(int) * (size_t)N_NODES * CAPB);

  // --- cooperative path: whole pipeline in one kernel ---
  int maxB = 0;
  hipError_t oerr = hipOccupancyMaxActiveBlocksPerMultiprocessor(
      &maxB, mega_k, 256, 0);
  bool coop_ok = (oerr == hipSuccess && maxB >= 1);
  if (coop_ok){
    int G = maxB * 256;           // 256 CUs
    if (G > 1024) G = 1024;       // 4 blocks/CU is plenty
    void* args[] = {&p};
    hipError_t lerr = hipLaunchCooperativeKernel(
        mega_k, dim3(G), dim3(256), args, 0, stream);
    if (lerr == hipSuccess) return;
  }

  // --- fallback: the proven 7-dispatch pipeline ---
  prep0_k<<<185, 256, 0, stream>>>(p.W0, p.pe0, p.Wt0, p.PW, p.deg);
  fused0_k<<<G0_NB + HIST_NB + 134, 256, 0, stream>>>(p);

  dim3 ggrid(4, (N_NODES + 127) / 128);
  int agrid = AGG_NB;

  agg4_k<<<agrid, 256, 0, stream>>>(p.fth, p.a1, p.a2, p.deg, p.esrc,
                                    p.hbuf, nullptr, 0);
  gemm_k<_Float16><<<ggrid, 256, 0, stream>>>(
      p.hbuf, p.Wt1, p.PW + 3 * FDIM, p.pos, p.al1, p.ar1, p.fth, p.a1, p.a2, 256);
  agg4_k<<<agrid, 256, 0, stream>>>(p.fth, p.a1, p.a2, p.deg, p.esrc,
                                    p.hbuf, nullptr, 0);
  gemm_k<_Float16><<<ggrid, 256, 0, stream>>>(
      p.hbuf, p.Wt2, p.PW + 6 * FDIM, p.pos, p.al2, p.ar2, p.fth, p.a1, p.a2, 256);
  agg4_k<<<agrid, 256, 0, stream>>>(p.fth, p.a1, p.a2, p.deg, p.esrc,
                                    nullptr, p.out, 1);
}

// Round 3
// 315.505 us; speedup vs baseline: 2.4801x; 2.4801x over previous
//
#include <hip/hip_runtime.h>
#include <hip/hip_fp16.h>
#include <math.h>

#define N_NODES 30000
#define N_EDGES 480000
#define HEADS 4
#define DHEAD 64
#define FDIM 256   // HEADS * DHEAD
#define POSD 32
#define CAPB 96            // bucket capacity (max observed degree ~45)
#define HIST_NB 1875       // 1875 blocks x 256 = 480000 edges
#define G0_NB 940          // gemm blocks: 4 heads x 235 row-blocks
#define ROWS_PB 16         // aggemm rows per block: 30000/16 = 1875 exactly
#define LDS_STRIDE 264     // halfs; 528B row stride, 16B-aligned

typedef _Float16 half8 __attribute__((ext_vector_type(8)));
typedef float floatx4 __attribute__((ext_vector_type(4)));

__device__ __forceinline__ float lrelu(float x){ return x > 0.f ? x : 0.2f * x; }

struct h4 { __half2 a, b; };
struct h4s { _Float16 h[4]; };

// ---------------- GEMM body (layer 0, reads fp32 features) -----------------
// One head per tile-x (64 cols), 128 rows per tile-y; 4 waves x 32 rows.
template<typename T>
__device__ __forceinline__ void gemm_body(
    int bx, int by, const T* __restrict__ A, const _Float16* __restrict__ Wt,
    const float* __restrict__ PW, const int* __restrict__ pos,
    const float* __restrict__ al, const float* __restrict__ arw,
    _Float16* __restrict__ Ch, float* __restrict__ a1, float* __restrict__ a2,
    int K){
  int t = threadIdx.x;
  int w = t >> 6;
  int lane = t & 63;
  int lm = lane & 15;
  int kq = lane >> 4;
  int h = bx;
  int rowBase = by * 128 + w * 32;
  int colBase = h * DHEAD;

  floatx4 acc[2][4] = {};

  const T* Ar[2];
#pragma unroll
  for (int r = 0; r < 2; r++)
    Ar[r] = A + (size_t)min(rowBase + r * 16 + lm, N_NODES - 1) * K;
  const _Float16* Bp[4];
#pragma unroll
  for (int j = 0; j < 4; j++)
    Bp[j] = Wt + (size_t)(colBase + j * 16 + lm) * K;

  for (int kb = 0; kb < K; kb += 32){
    int ko = kb + kq * 8;
    half8 bf[4];
#pragma unroll
    for (int j = 0; j < 4; j++) bf[j] = *(const half8*)(Bp[j] + ko);
#pragma unroll
    for (int r = 0; r < 2; r++){
      half8 af;
      if constexpr (sizeof(T) == 2){
        af = *(const half8*)(Ar[r] + ko);
      } else {
        float4 u0 = *(const float4*)(Ar[r] + ko);
        float4 u1 = *(const float4*)(Ar[r] + ko + 4);
        af[0] = (_Float16)u0.x; af[1] = (_Float16)u0.y;
        af[2] = (_Float16)u0.z; af[3] = (_Float16)u0.w;
        af[4] = (_Float16)u1.x; af[5] = (_Float16)u1.y;
        af[6] = (_Float16)u1.z; af[7] = (_Float16)u1.w;
      }
#pragma unroll
      for (int j = 0; j < 4; j++)
        acc[r][j] = __builtin_amdgcn_mfma_f32_16x16x32_f16(af, bf[j], acc[r][j], 0, 0, 0);
    }
  }

  float alw[4], arr[4];
#pragma unroll
  for (int j = 0; j < 4; j++){
    int col = j * 16 + lm;
    alw[j] = al [h * DHEAD + col];
    arr[j] = arw[h * DHEAD + col];
  }

#pragma unroll
  for (int r = 0; r < 2; r++){
#pragma unroll
    for (int p = 0; p < 4; p++){
      int row = rowBase + r * 16 + kq * 4 + p;
      if (row < N_NODES){
        int pz = pos[row];
        const float* pwb = PW + pz * FDIM + colBase;
        float s1 = 0.f, s2 = 0.f;
#pragma unroll
        for (int j = 0; j < 4; j++){
          float v = acc[r][j][p] + pwb[j * 16 + lm];
          Ch[(size_t)row * FDIM + colBase + j * 16 + lm] = (_Float16)v;
          s1 = fmaf(v, alw[j], s1);
          s2 = fmaf(v, arr[j], s2);
        }
#pragma unroll
        for (int o2 = 1; o2 <= 8; o2 <<= 1){
          s1 += __shfl_xor(s1, o2, 64);
          s2 += __shfl_xor(s2, o2, 64);
        }
        if (lm == 0){
          a1[row * HEADS + h] = s1;
          a2[row * HEADS + h] = s2;
        }
      }
    }
  }
}

// ---------------- agg core: one wave computes one node's 256-d output ------
// Result (pre-activation) left in acc (per-lane float4 for cols lane*4..+4).
__device__ __forceinline__ float4 agg_node(
    int n, const _Float16* __restrict__ ft, const float* __restrict__ a1,
    const float* __restrict__ a2, const int* __restrict__ degv,
    const int* __restrict__ esrc, int lane){
  int jb = n * CAPB;
  int deg = min(degv[n], CAPB);
  int eidx = lane & 15, h = lane >> 4;
  int hsel = h << 4;
  float a2n = a2[n * HEADS + h];
  float4 acc = make_float4(0.f, 0.f, 0.f, 0.f);
  const _Float16* ftl = ft + lane * 4;

  if (deg <= 64){
    int sreg[4]; float wreg[4];
    float m = -INFINITY;
#pragma unroll
    for (int r = 0; r < 4; r++){
      int idx = eidx + r * 16;
      int s = (idx < deg) ? esrc[jb + idx] : 0;
      sreg[r] = s;
      float e = (idx < deg) ? lrelu(a1[s * HEADS + h] + a2n) : -INFINITY;
      wreg[r] = e;
      m = fmaxf(m, e);
    }
    m = fmaxf(m, __shfl_xor(m, 1, 64));
    m = fmaxf(m, __shfl_xor(m, 2, 64));
    m = fmaxf(m, __shfl_xor(m, 4, 64));
    m = fmaxf(m, __shfl_xor(m, 8, 64));
    float ss = 0.f;
#pragma unroll
    for (int r = 0; r < 4; r++){
      int idx = eidx + r * 16;
      float tv = (idx < deg) ? __expf(wreg[r] - m) : 0.f;
      wreg[r] = tv;
      ss += tv;
    }
    ss += __shfl_xor(ss, 1, 64);
    ss += __shfl_xor(ss, 2, 64);
    ss += __shfl_xor(ss, 4, 64);
    ss += __shfl_xor(ss, 8, 64);
    float inv = (ss > 0.f) ? 1.f / ss : 0.f;
#pragma unroll
    for (int r = 0; r < 4; r++) wreg[r] *= inv;

#pragma unroll
    for (int r = 0; r < 4; r++){
      if (r * 16 >= deg) break;
      int lim = deg - r * 16; if (lim > 16) lim = 16;
      float wr = wreg[r]; int sr = sreg[r];
      int jj = 0;
      for (; jj + 8 <= lim; jj += 8){
        float w8[8]; int s8[8]; h4 f8[8];
#pragma unroll
        for (int u = 0; u < 8; u++){
          w8[u] = __shfl(wr, (jj + u) | hsel, 64);
          s8[u] = __shfl(sr, jj + u, 64);
        }
#pragma unroll
        for (int u = 0; u < 8; u++)
          f8[u] = *(const h4*)(ftl + (size_t)s8[u] * FDIM);
#pragma unroll
        for (int u = 0; u < 8; u++){
          float2 fa = __half22float2(f8[u].a), fb = __half22float2(f8[u].b);
          acc.x = fmaf(w8[u], fa.x, acc.x);
          acc.y = fmaf(w8[u], fa.y, acc.y);
          acc.z = fmaf(w8[u], fb.x, acc.z);
          acc.w = fmaf(w8[u], fb.y, acc.w);
        }
      }
      for (; jj < lim; jj += 4){
        float w4[4]; int s4[4]; h4 f4[4];
#pragma unroll
        for (int u = 0; u < 4; u++){
          w4[u] = __shfl(wr, (jj + u) | hsel, 64);
          s4[u] = __shfl(sr, jj + u, 64);
        }
#pragma unroll
        for (int u = 0; u < 4; u++)
          f4[u] = *(const h4*)(ftl + (size_t)s4[u] * FDIM);
#pragma unroll
        for (int u = 0; u < 4; u++){
          float2 fa = __half22float2(f4[u].a), fb = __half22float2(f4[u].b);
          acc.x = fmaf(w4[u], fa.x, acc.x);
          acc.y = fmaf(w4[u], fa.y, acc.y);
          acc.z = fmaf(w4[u], fb.x, acc.z);
          acc.w = fmaf(w4[u], fb.y, acc.w);
        }
      }
    }
  } else {
    float m = -INFINITY;
    for (int idx = eidx; idx < deg; idx += 16){
      int s = esrc[jb + idx];
      m = fmaxf(m, lrelu(a1[s * HEADS + h] + a2n));
    }
    m = fmaxf(m, __shfl_xor(m, 1, 64));
    m = fmaxf(m, __shfl_xor(m, 2, 64));
    m = fmaxf(m, __shfl_xor(m, 4, 64));
    m = fmaxf(m, __shfl_xor(m, 8, 64));
    float ss = 0.f;
    for (int idx = eidx; idx < deg; idx += 16){
      int s = esrc[jb + idx];
      ss += __expf(lrelu(a1[s * HEADS + h] + a2n) - m);
    }
    ss += __shfl_xor(ss, 1, 64);
    ss += __shfl_xor(ss, 2, 64);
    ss += __shfl_xor(ss, 4, 64);
    ss += __shfl_xor(ss, 8, 64);
    float inv = (ss > 0.f) ? 1.f / ss : 0.f;
    for (int j = 0; j < deg; j++){
      int sj = esrc[jb + j];
      float e = lrelu(a1[sj * HEADS + h] + a2n);
      float wj = __expf(e - m) * inv;
      h4 f = *(const h4*)(ftl + (size_t)sj * FDIM);
      float2 fa = __half22float2(f.a), fb = __half22float2(f.b);
      acc.x = fmaf(wj, fa.x, acc.x);
      acc.y = fmaf(wj, fa.y, acc.y);
      acc.z = fmaf(wj, fb.x, acc.z);
      acc.w = fmaf(wj, fb.y, acc.w);
    }
  }
  return acc;
}

// ---------------- fused agg + gemm (hidden layers 1/2) ---------------------
// Block = 16 rows (grid 1875, no tail). Phase 1: 4 waves x 4 nodes agg ->
// ELU -> fp16 -> LDS [16][264]. Phase 2: wave w = head w, 16x64 MFMA tile,
// K=256 from LDS; epilogue adds PW bias, writes ftout + a1/a2 (next-layer
// buffers; double-buffered vs gather inputs to avoid cross-block races).
__global__ __launch_bounds__(256, 2) void aggemm_k(
    const _Float16* __restrict__ ftin, const float* __restrict__ a1in,
    const float* __restrict__ a2in, const int* __restrict__ degv,
    const int* __restrict__ esrc, const _Float16* __restrict__ Wt,
    const float* __restrict__ PW, const int* __restrict__ pos,
    const float* __restrict__ al, const float* __restrict__ arw,
    _Float16* __restrict__ ftout, float* __restrict__ a1out,
    float* __restrict__ a2out){
  __shared__ _Float16 As[ROWS_PB * LDS_STRIDE];
  int t = threadIdx.x;
  int wv = t >> 6;
  int lane = t & 63;
  int rb = blockIdx.x * ROWS_PB;

  // ---- phase 1: aggregation (one wave per node, 4 nodes per wave) ----
#pragma unroll
  for (int i = 0; i < 4; i++){
    int rowLocal = wv * 4 + i;
    int n = rb + rowLocal;            // always < 30000 (1875*16 exact)
    float4 acc = agg_node(n, ftin, a1in, a2in, degv, esrc, lane);
    // ELU + fp16
    acc.x = acc.x > 0.f ? acc.x : (__expf(acc.x) - 1.f);
    acc.y = acc.y > 0.f ? acc.y : (__expf(acc.y) - 1.f);
    acc.z = acc.z > 0.f ? acc.z : (__expf(acc.z) - 1.f);
    acc.w = acc.w > 0.f ? acc.w : (__expf(acc.w) - 1.f);
    h4s u;
    u.h[0] = (_Float16)acc.x; u.h[1] = (_Float16)acc.y;
    u.h[2] = (_Float16)acc.z; u.h[3] = (_Float16)acc.w;
    *(h4s*)&As[rowLocal * LDS_STRIDE + lane * 4] = u;
  }
  __syncthreads();

  // ---- phase 2: 16x256 gemm, wave = head ----
  int lm = lane & 15;
  int kq = lane >> 4;
  int h = wv;
  int colBase = h * DHEAD;

  floatx4 acc[4] = {};
  const _Float16* Bp[4];
#pragma unroll
  for (int j = 0; j < 4; j++)
    Bp[j] = Wt + (size_t)(colBase + j * 16 + lm) * 256;

  for (int kb = 0; kb < 256; kb += 32){
    int ko = kb + kq * 8;
    half8 af = *(const half8*)&As[lm * LDS_STRIDE + ko];
    half8 bf[4];
#pragma unroll
    for (int j = 0; j < 4; j++) bf[j] = *(const half8*)(Bp[j] + ko);
#pragma unroll
    for (int j = 0; j < 4; j++)
      acc[j] = __builtin_amdgcn_mfma_f32_16x16x32_f16(af, bf[j], acc[j], 0, 0, 0);
  }

  float alw[4], arr[4];
#pragma unroll
  for (int j = 0; j < 4; j++){
    int col = j * 16 + lm;
    alw[j] = al [h * DHEAD + col];
    arr[j] = arw[h * DHEAD + col];
  }

#pragma unroll
  for (int p = 0; p < 4; p++){
    int row = rb + kq * 4 + p;        // always < 30000
    int pz = pos[row];
    const float* pwb = PW + pz * FDIM + colBase;
    float s1 = 0.f, s2 = 0.f;
#pragma unroll
    for (int j = 0; j < 4; j++){
      float v = acc[j][p] + pwb[j * 16 + lm];
      ftout[(size_t)row * FDIM + colBase + j * 16 + lm] = (_Float16)v;
      s1 = fmaf(v, alw[j], s1);
      s2 = fmaf(v, arr[j], s2);
    }
#pragma unroll
    for (int o2 = 1; o2 <= 8; o2 <<= 1){
      s1 += __shfl_xor(s1, o2, 64);
      s2 += __shfl_xor(s2, o2, 64);
    }
    if (lm == 0){
      a1out[row * HEADS + h] = s1;
      a2out[row * HEADS + h] = s2;
    }
  }
}

// ---------------- standalone agg (final layer: head-mean -> out) -----------
__global__ __launch_bounds__(256) void aggfin_k(
    const _Float16* __restrict__ ft, const float* __restrict__ a1,
    const float* __restrict__ a2, const int* __restrict__ degv,
    const int* __restrict__ esrc, float* __restrict__ outf){
  int wv = threadIdx.x >> 6;
  int lane = threadIdx.x & 63;
  int n = blockIdx.x * 4 + wv;
  if (n >= N_NODES) return;
  float4 acc = agg_node(n, ft, a1, a2, degv, esrc, lane);
#pragma unroll
  for (int o2 = 16; o2 <= 32; o2 <<= 1){
    acc.x += __shfl_xor(acc.x, o2, 64);
    acc.y += __shfl_xor(acc.y, o2, 64);
    acc.z += __shfl_xor(acc.z, o2, 64);
    acc.w += __shfl_xor(acc.w, o2, 64);
  }
  if (lane < 16){
    float4 o;
    o.x = acc.x * 0.25f; o.y = acc.y * 0.25f;
    o.z = acc.z * 0.25f; o.w = acc.w * 0.25f;
    *(float4*)&outf[(size_t)n * DHEAD + lane * 4] = o;
  }
}

// ---------------- pre-kernel: W0 transpose + PW0 + deg zero ----------------
__global__ __launch_bounds__(256) void prep0_k(
    const float* __restrict__ W0, const float* __restrict__ pe0,
    _Float16* __restrict__ T0, float* __restrict__ PW, int* __restrict__ deg){
  int blk = blockIdx.x, n = threadIdx.x;
  if (blk < 64){
    for (int k = blk; k < 128; k += 64)
      T0[(size_t)n * 128 + k] = (_Float16)W0[(size_t)k * FDIM + n];
  } else if (blk < 67){
    int v = blk - 64;
    float s = 0.f;
#pragma unroll
    for (int k = 0; k < POSD; k++)
      s = fmaf(pe0[v * POSD + k], W0[(size_t)(128 + k) * FDIM + n], s);
    PW[v * FDIM + n] = s;
  } else {
    int i = (blk - 67) * 256 + n;
    if (i < N_NODES) deg[i] = 0;
  }
}

// ---------------- fused dispatch: gemm0 + edge scatter + layer-1/2 prep ----
__global__ __launch_bounds__(256, 2) void fused0_k(
    const float* __restrict__ A, const _Float16* __restrict__ Wt0,
    const float* __restrict__ PW0, const int* __restrict__ pos,
    const float* __restrict__ al0, const float* __restrict__ ar0,
    _Float16* __restrict__ Ch, float* __restrict__ a1, float* __restrict__ a2,
    const int* __restrict__ src, const int* __restrict__ dst,
    int* __restrict__ deg, int* __restrict__ esrc,
    const float* __restrict__ W1, const float* __restrict__ W2,
    _Float16* __restrict__ T1, _Float16* __restrict__ T2,
    const float* __restrict__ pe1, const float* __restrict__ pe2,
    float* __restrict__ PWall){
  int blk = blockIdx.x;
  if (blk < G0_NB){
    gemm_body<float>(blk & 3, blk >> 2, A, Wt0, PW0, pos, al0, ar0,
                     Ch, a1, a2, 128);
  } else if (blk < G0_NB + HIST_NB){
    int e = (blk - G0_NB) * 256 + threadIdx.x;
    if (e < N_EDGES){
      int d = dst[e];
      int slot = atomicAdd(&deg[d], 1);
      if (slot < CAPB) esrc[d * CAPB + slot] = src[e];
    }
  } else if (blk < G0_NB + HIST_NB + 128){
    int q = blk - G0_NB - HIST_NB;
    int l = q >> 6, kk0 = q & 63;
    const float* W = l == 0 ? W1 : W2;
    _Float16* T    = l == 0 ? T1 : T2;
    int n = threadIdx.x;
    for (int k = kk0; k < 256; k += 64)
      T[(size_t)n * 256 + k] = (_Float16)W[(size_t)k * FDIM + n];
  } else {
    int q = blk - G0_NB - HIST_NB - 128;
    int layer = q / 3 + 1, v = q % 3;
    const float* W  = layer == 1 ? W1 : W2;
    const float* pe = layer == 1 ? pe1 : pe2;
    int j = threadIdx.x;
    float s = 0.f;
#pragma unroll
    for (int k = 0; k < POSD; k++)
      s = fmaf(pe[v * POSD + k], W[(size_t)(256 + k) * FDIM + j], s);
    PWall[(layer * 3 + v) * FDIM + j] = s;
  }
}

// ---------------- launch ----------------
extern "C" void kernel_launch(void* const* d_in, const int* in_sizes, int n_in,
                              void* d_out, int out_size, void* d_ws, size_t ws_size,
                              hipStream_t stream){
  const float* features = (const float*)d_in[0];
  const float* W0  = (const float*)d_in[1];
  const float* al0 = (const float*)d_in[2];
  const float* ar0 = (const float*)d_in[3];
  const float* pe0 = (const float*)d_in[4];
  const float* W1  = (const float*)d_in[5];
  const float* al1 = (const float*)d_in[6];
  const float* ar1 = (const float*)d_in[7];
  const float* pe1 = (const float*)d_in[8];
  const float* W2  = (const float*)d_in[9];
  const float* al2 = (const float*)d_in[10];
  const float* ar2 = (const float*)d_in[11];
  const float* pe2 = (const float*)d_in[12];
  const int* srcv  = (const int*)d_in[13];
  const int* dstv  = (const int*)d_in[14];
  const int* posv  = (const int*)d_in[15];
  float* out = (float*)d_out;

  char* wp = (char*)d_ws;
  auto alloc = [&](size_t bytes){
    void* q = (void*)wp;
    wp += (bytes + 255) & ~(size_t)255;
    return q;
  };
  _Float16* F0  = (_Float16*)alloc(sizeof(_Float16) * (size_t)N_NODES * FDIM);
  _Float16* F1  = (_Float16*)alloc(sizeof(_Float16) * (size_t)N_NODES * FDIM);
  _Float16* Wt0 = (_Float16*)alloc(sizeof(_Float16) * 256 * 128);
  _Float16* Wt1 = (_Float16*)alloc(sizeof(_Float16) * 256 * 256);
  _Float16* Wt2 = (_Float16*)alloc(sizeof(_Float16) * 256 * 256);
  float* a1A = (float*)alloc(sizeof(float) * N_NODES * HEADS);
  float* a2A = (float*)alloc(sizeof(float) * N_NODES * HEADS);
  float* a1B = (float*)alloc(sizeof(float) * N_NODES * HEADS);
  float* a2B = (float*)alloc(sizeof(float) * N_NODES * HEADS);
  float* PW  = (float*)alloc(sizeof(float) * 9 * FDIM);
  int*   deg = (int*)alloc(sizeof(int) * N_NODES);
  int*   esrc= (int*)alloc(sizeof(int) * (size_t)N_NODES * CAPB);

  // D1: W0 transpose + PW0 + deg:=0
  prep0_k<<<185, 256, 0, stream>>>(W0, pe0, Wt0, PW, deg);

  // D2: layer-0 gemm overlapped with edge scatter + layer-1/2 prep
  fused0_k<<<G0_NB + HIST_NB + 134, 256, 0, stream>>>(
      features, Wt0, PW, posv, al0, ar0, F0, a1A, a2A,
      srcv, dstv, deg, esrc, W1, W2, Wt1, Wt2, pe1, pe2, PW);

  // D3: agg(layer0) + gemm(layer1): gather F0/a1A -> write F1/a1B
  aggemm_k<<<1875, 256, 0, stream>>>(
      F0, a1A, a2A, deg, esrc, Wt1, PW + 3 * FDIM, posv, al1, ar1,
      F1, a1B, a2B);

  // D4: agg(layer1) + gemm(layer2): gather F1/a1B -> write F0/a1A
  aggemm_k<<<1875, 256, 0, stream>>>(
      F1, a1B, a2B, deg, esrc, Wt2, PW + 6 * FDIM, posv, al2, ar2,
      F0, a1A, a2A);

  // D5: final aggregation, head-mean -> out
  aggfin_k<<<(N_NODES + 3) / 4, 256, 0, stream>>>(
      F0, a1A, a2A, deg, esrc, out);
}